// Round 5
// baseline (1846.027 us; speedup 1.0000x reference)
//
#include <hip/hip_runtime.h>

typedef unsigned short u16;
typedef unsigned int   u32;

__device__ __forceinline__ float bf2f(u16 h){ return __uint_as_float(((u32)h)<<16); }
__device__ __forceinline__ u16 f2bf(float f){
  u32 u = __float_as_uint(f);
  u32 r = (u + 0x7FFFu + ((u>>16)&1u)) >> 16;
  return (u16)r;
}
// weight load: bf16 or fp32 selected by runtime flag (wave-uniform branch)
__device__ __forceinline__ float ldw(const void* p, size_t i, int bf){
  return bf ? bf2f(((const u16*)p)[i]) : ((const float*)p)[i];
}

// ---------------- constants ----------------
#define BTASK   2048
#define KTOT    10320      // 6*1720
#define NP      40
#define KS      30         // k-split segments of the main pass
#define SEGLEN  344        // 30*344 = 10320; chunks 5x64 + 24

// ws byte offsets (256-aligned). Peak usage 11,856,768 B (~11.3 MiB).
#define OFF_PIX  0u          // 36000
#define OFF_WF   36096u      // 1,658,880 (10368 rows x 40 f32; rows >=10320 stay 0)
#define OFF_HR   1694976u    // 288,000
#define OFF_WO   1982976u    // 17,200
#define OFF_RR   2000384u    // 8,000
#define OFF_BF   2008576u    // 160
#define OFF_FLG  2008832u    // 4
#define OFF_O12  2009088u    // 17,200
// transients (all dead before main pass)
#define OFF_S3   2026368u    // 81,920
#define OFF_S2   2108288u    // 163,840
#define OFF_HF   2272128u    // 288,000
#define OFF_R3   2560128u    // 288,000
#define OFF_R2   2848128u    // 960,000
#define OFF_R1   3808128u    // 960,000  (ends 4,768,128)
#define OFF_PART 2026368u    // 9,830,400 (aliases S3..R1; ends 11,856,768)

// ---------------- dtype detect: point_mask is all-ones by construction
__global__ void detect_kernel(const u32* __restrict__ m, int* __restrict__ flag){
  if (threadIdx.x == 0) flag[0] = (m[0] == 0x3F803F80u) ? 1 : 0;
}

// ---------------- pix[c,i,j] = w0*(wc[c]+bc) + w1*(wx[i]+bx) + w2*(wy[j]+by) + bcomb
__global__ void pix_kernel(const void* wc, const void* bc, const void* wx, const void* bx,
                           const void* wy, const void* by, const void* wcb, const void* bcb,
                           const int* __restrict__ flag, float* __restrict__ pixf){
  int bf = flag[0];
  int e = blockIdx.x*256 + threadIdx.x;
  if (e >= 9000) return;
  int c = e/900, r = e%900, i = r/30, j = r%30;
  float col = ldw(wc,c,bf) + ldw(bc,0,bf);
  float xe  = ldw(wx,i,bf) + ldw(bx,0,bf);
  float ye  = ldw(wy,j,bf) + ldw(by,0,bf);
  pixf[e] = ldw(wcb,0,bf)*col + ldw(wcb,1,bf)*xe + ldw(wcb,2,bf)*ye + ldw(bcb,0,bf);
}

// ---------------- naive GEMM: C[m*N+n] = sum_k A[m*K+k]*B[k*N+n]
// AW/BW: operand is a weight (dtype per flag) vs fp32 workspace.
template<int AW, int BW>
__global__ void ngemm(const void* __restrict__ A, const void* __restrict__ Bv,
                      float* __restrict__ C, int M, int N, int K,
                      const int* __restrict__ flag){
  int bf = flag[0];
  int oi = blockIdx.x*256 + threadIdx.x;
  if (oi >= M*N) return;
  int m = oi / N, n = oi % N;
  const float* Af = (const float*)A;
  const float* Bf = (const float*)Bv;
  float s = 0.f;
  for (int k = 0; k < K; k++) {
    float a = AW ? ldw(A, (size_t)m*K + k, bf) : Af[(size_t)m*K + k];
    float b = BW ? ldw(Bv, (size_t)k*N + n, bf) : Bf[(size_t)k*N + n];
    s += a*b;
  }
  C[oi] = s;
}

// ---------------- Hresh[j*240 + p*40 + n] = Whead[(p*300+j)*40 + n]
__global__ void repack_kernel(const float* __restrict__ Hfp, float* __restrict__ Hresh){
  int oi = blockIdx.x*256 + threadIdx.x;
  if (oi >= 72000) return;
  int j = oi/240, c = oi%240, p = c/40, n = c%40;
  Hresh[oi] = Hfp[(size_t)(p*300+j)*40 + n];
}

// ---------------- Wfull[k*40+n], k = p*1720+g*86+t:  sum_d wobj[t,d]*R1[(g*50+d)][p*40+n]
__global__ void wfull_kernel(const float* __restrict__ wobj, const float* __restrict__ R1,
                             float* __restrict__ Wfull){
  int oi = blockIdx.x*256 + threadIdx.x;
  if (oi >= KTOT*NP) return;
  int k = oi/NP, n = oi%NP;
  int p = k/1720, r = k%1720, g = r/86, t = r%86;
  float s = 0.f;
  for (int d = 0; d < 50; d++)
    s += wobj[t*50 + d] * R1[(size_t)(g*50+d)*240 + p*40 + n];
  Wfull[oi] = s;
}

// ---------------- r1red[j*40+n] = sum_{g<20,p<6} R1[(g*50+j)][p*40+n]
__global__ void r1red_kernel(const float* __restrict__ R1, float* __restrict__ r1red){
  int oi = blockIdx.x*256 + threadIdx.x;
  if (oi >= 2000) return;
  int j = oi/40, n = oi%40;
  float s = 0.f;
  for (int g = 0; g < 20; g++)
    for (int p = 0; p < 6; p++)
      s += R1[(size_t)(g*50+j)*240 + p*40 + n];
  r1red[oi] = s;
}

// ---------------- full bias composition (single block)
__global__ void bias_kernel(const void* ob1, const void* ob2, const void* ob3,
                            const void* oW2, const void* oW3,
                            const void* iob1, const void* iob2, const void* iob3,
                            const void* ioW2, const void* ioW3,
                            const void* nb1, const void* nb2, const void* nb3, const void* nb4,
                            const void* nW2, const void* nW3, const void* nW4,
                            const int* __restrict__ flag,
                            const float* __restrict__ Hresh, const float* __restrict__ r1red,
                            float* __restrict__ biasf){
  __shared__ float bo1[50], bobj[50], bi1[300], bio[300], bn1[512], bn2[256], bh[40];
  __shared__ float hsum[12000];
  int bf = flag[0];
  int tid = threadIdx.x;
  for (int n = tid; n < 50; n += 256) {
    float s = ldw(ob2,n,bf);
    for (int t = 0; t < 86; t++) s += ldw(ob1,t,bf)*ldw(oW2,(size_t)t*50+n,bf);
    bo1[n] = s;
  }
  for (int n = tid; n < 300; n += 256) {
    float s = ldw(iob2,n,bf);
    for (int k = 0; k < 1000; k++) s += ldw(iob1,k,bf)*ldw(ioW2,(size_t)k*300+n,bf);
    bi1[n] = s;
  }
  for (int n = tid; n < 512; n += 256) {
    float s = ldw(nb2,n,bf);
    for (int k = 0; k < 1024; k++) s += ldw(nb1,k,bf)*ldw(nW2,(size_t)k*512+n,bf);
    bn1[n] = s;
  }
  for (int e = tid; e < 12000; e += 256) {
    int j = e/40, n = e%40;
    float s = 0.f;
    #pragma unroll
    for (int p = 0; p < 6; p++) s += Hresh[j*240 + p*40 + n];
    hsum[e] = s;
  }
  __syncthreads();
  for (int n = tid; n < 50; n += 256) {
    float s = ldw(ob3,n,bf);
    for (int j = 0; j < 50; j++) s += bo1[j]*ldw(oW3,(size_t)j*50+n,bf);
    bobj[n] = s;
  }
  for (int n = tid; n < 300; n += 256) {
    float s = ldw(iob3,n,bf);
    for (int j = 0; j < 300; j++) s += bi1[j]*ldw(ioW3,(size_t)j*300+n,bf);
    bio[n] = s;
  }
  for (int n = tid; n < 256; n += 256) {
    float s = ldw(nb3,n,bf);
    for (int j = 0; j < 512; j++) s += bn1[j]*ldw(nW3,(size_t)j*256+n,bf);
    bn2[n] = s;
  }
  __syncthreads();
  for (int n = tid; n < 40; n += 256) {
    float s = ldw(nb4,n,bf);
    for (int j = 0; j < 256; j++) s += bn2[j]*ldw(nW4,(size_t)j*40+n,bf);
    bh[n] = s;
  }
  __syncthreads();
  if (tid < 40) {
    int n = tid;
    float s = bh[n];
    for (int j = 0; j < 300; j++) s += bio[j]*hsum[j*40+n];
    for (int j = 0; j < 50; j++)  s += bobj[j]*r1red[j*40+n];
    biasf[n] = s;
  }
}

// ---------------- main: gather v = pix[c,i,j]*mask, GEMV vs Wfull, k-split partials
__launch_bounds__(320, 2)
__global__ void main_gather(const int* __restrict__ c_idx, const int* __restrict__ i_idx,
                            const int* __restrict__ j_idx, const void* __restrict__ maskv,
                            const float* __restrict__ pixf, const float* __restrict__ Wfull,
                            const int* __restrict__ flag, float* __restrict__ part){
  __shared__ float pixs[9000];
  __shared__ float vbuf[64*129];   // [k][task], +1 pad breaks bank alignment
  int bf = flag[0];
  const u16*   mh = (const u16*)maskv;
  const float* mf = (const float*)maskv;
  int tid = threadIdx.x;
  for (int e = tid; e < 9000; e += 320) pixs[e] = pixf[e];
  int task0 = blockIdx.x << 7;           // 16 blocks x 128 tasks
  int kseg0 = blockIdx.y * SEGLEN;       // 30 segments x 344
  int lane = tid & 63;
  int ng = __builtin_amdgcn_readfirstlane(tid >> 6);   // wave 0..4 -> 8 output cols
  float acc[2][8] = {};
  __syncthreads();
  for (int cb = 0; cb < 6; cb++) {
    int kc0 = kseg0 + cb*64;
    int kc = (cb == 5) ? 24 : 64;
    int nq = kc >> 2;
    if (kc < 64)
      for (int e = tid; e < (64-kc)*129; e += 320) vbuf[kc*129 + e] = 0.f;
    int totq = nq << 7;
    for (int e4 = tid; e4 < totq; e4 += 320) {
      int t, q;
      if (nq == 16) { t = e4 >> 4; q = e4 & 15; }
      else          { t = (int)((u32)e4 / 6u); q = e4 - t*6; }
      int gk = kc0 + (q << 2);
      size_t gb = (size_t)(task0 + t)*KTOT + gk;
      int4 c4 = *(const int4*)(c_idx + gb);
      int4 i4 = *(const int4*)(i_idx + gb);
      int4 j4 = *(const int4*)(j_idx + gb);
      float mv[4];
      if (bf) {
        ushort4 m4 = *(const ushort4*)(mh + gb);
        mv[0]=bf2f(m4.x); mv[1]=bf2f(m4.y); mv[2]=bf2f(m4.z); mv[3]=bf2f(m4.w);
      } else {
        float4 m4 = *(const float4*)(mf + gb);
        mv[0]=m4.x; mv[1]=m4.y; mv[2]=m4.z; mv[3]=m4.w;
      }
      int cc[4] = {c4.x,c4.y,c4.z,c4.w};
      int ii[4] = {i4.x,i4.y,i4.z,i4.w};
      int jj[4] = {j4.x,j4.y,j4.z,j4.w};
      int kk = q << 2;
      #pragma unroll
      for (int x = 0; x < 4; x++)
        vbuf[(kk+x)*129 + t] = pixs[cc[x]*900 + ii[x]*30 + jj[x]] * mv[x];
    }
    __syncthreads();
    const float* Wk = Wfull + (size_t)kc0*NP + ng*8;
    for (int k = 0; k < 64; k++) {
      float v0 = vbuf[k*129 + 2*lane];
      float v1 = vbuf[k*129 + 2*lane + 1];
      const float* w = Wk + k*NP;
      float wv[8];
      #pragma unroll
      for (int n = 0; n < 8; n++) wv[n] = w[n];
      #pragma unroll
      for (int n = 0; n < 8; n++) { acc[0][n] += v0*wv[n]; acc[1][n] += v1*wv[n]; }
    }
    __syncthreads();
  }
  size_t base = ((size_t)blockIdx.y*BTASK + task0 + (lane<<1))*NP + ng*8;
  #pragma unroll
  for (int i = 0; i < 2; i++) {
    float4 x = { acc[i][0], acc[i][1], acc[i][2], acc[i][3] };
    float4 y = { acc[i][4], acc[i][5], acc[i][6], acc[i][7] };
    *(float4*)(part + base + i*NP)     = x;
    *(float4*)(part + base + i*NP + 4) = y;
  }
}

// ---------------- reduce partials + bias, emit FP32 (reference output dtype)
__global__ void main_reduce(const float* __restrict__ part, const float* __restrict__ biasf,
                            float* __restrict__ out){
  int oi = blockIdx.x*256 + threadIdx.x;
  if (oi >= BTASK*NP) return;
  float s = biasf[oi % NP];
  for (int z = 0; z < KS; z++) s += part[(size_t)z*(BTASK*NP) + oi];
  out[oi] = s;
}

extern "C" void kernel_launch(void* const* d_in, const int* in_sizes, int n_in,
                              void* d_out, int out_size, void* d_ws, size_t ws_size,
                              hipStream_t stream){
  const int* c_idx = (const int*)d_in[0];
  const int* i_idx = (const int*)d_in[1];
  const int* j_idx = (const int*)d_in[2];
  const void* mask = d_in[3];
  const void *w_color=d_in[4], *b_color=d_in[5], *w_x=d_in[6], *b_x=d_in[7];
  const void *w_y=d_in[8], *b_y=d_in[9], *w_comb=d_in[10], *b_comb=d_in[11];
  const void *oW1=d_in[12], *ob1=d_in[13], *oW2=d_in[14], *ob2=d_in[15];
  const void *oW3=d_in[16], *ob3=d_in[17];
  const void *ioW1=d_in[18], *iob1=d_in[19], *ioW2=d_in[20], *iob2=d_in[21];
  const void *ioW3=d_in[22], *iob3=d_in[23];
  const void *nW1=d_in[24], *nb1=d_in[25], *nW2=d_in[26], *nb2=d_in[27];
  const void *nW3=d_in[28], *nb3=d_in[29], *nW4=d_in[30], *nb4=d_in[31];

  char* ws = (char*)d_ws;
  float* pixf  = (float*)(ws + OFF_PIX);
  float* Wfull = (float*)(ws + OFF_WF);
  float* Hresh = (float*)(ws + OFF_HR);
  float* wobj  = (float*)(ws + OFF_WO);
  float* r1red = (float*)(ws + OFF_RR);
  float* biasf = (float*)(ws + OFF_BF);
  int*   flag  = (int*)  (ws + OFF_FLG);
  float* o12   = (float*)(ws + OFF_O12);
  float* S3p   = (float*)(ws + OFF_S3);
  float* S2p   = (float*)(ws + OFF_S2);
  float* Hfp   = (float*)(ws + OFF_HF);
  float* R3p   = (float*)(ws + OFF_R3);
  float* R2p   = (float*)(ws + OFF_R2);
  float* R1p   = (float*)(ws + OFF_R1);
  float* part  = (float*)(ws + OFF_PART);

  detect_kernel<<<1, 64, 0, stream>>>((const u32*)mask, flag);
  // zero Wfull incl pad rows 10320..10367 (read by the 24-wide tail chunks)
  hipMemsetAsync(ws + OFF_WF, 0, (size_t)10368*NP*4, stream);

  pix_kernel<<<36, 256, 0, stream>>>(w_color, b_color, w_x, b_x, w_y, b_y, w_comb, b_comb,
                                     flag, pixf);
  // head chain (right-assoc): S3 = nW3@nW4, S2 = nW2@S3, Whead = nW1@S2
  ngemm<1,1><<<80,  256, 0, stream>>>(nW3, nW4, S3p, 512, 40, 256, flag);
  ngemm<1,0><<<160, 256, 0, stream>>>(nW2, S3p, S2p, 1024, 40, 512, flag);
  ngemm<1,0><<<282, 256, 0, stream>>>(nW1, S2p, Hfp, 1800, 40, 1024, flag);
  repack_kernel<<<282, 256, 0, stream>>>(Hfp, Hresh);
  // io chain: R3 = ioW3@Hresh, R2 = ioW2@R3, R1 = ioW1@R2
  ngemm<1,0><<<282, 256, 0, stream>>>(ioW3, Hresh, R3p, 300, 240, 300, flag);
  ngemm<1,0><<<938, 256, 0, stream>>>(ioW2, R3p, R2p, 1000, 240, 300, flag);
  ngemm<1,0><<<938, 256, 0, stream>>>(ioW1, R2p, R1p, 1000, 240, 1000, flag);
  // obj chain: o12 = oW1@oW2, Wobj = o12@oW3
  ngemm<1,1><<<17, 256, 0, stream>>>(oW1, oW2, o12, 86, 50, 86, flag);
  ngemm<0,1><<<17, 256, 0, stream>>>(o12, oW3, wobj, 86, 50, 50, flag);
  // composed weight + bias
  wfull_kernel<<<1613, 256, 0, stream>>>(wobj, R1p, Wfull);
  r1red_kernel<<<8, 256, 0, stream>>>(R1p, r1red);
  bias_kernel<<<1, 256, 0, stream>>>(ob1, ob2, ob3, oW2, oW3,
                                     iob1, iob2, iob3, ioW2, ioW3,
                                     nb1, nb2, nb3, nb4, nW2, nW3, nW4,
                                     flag, Hresh, r1red, biasf);
  // main pass
  main_gather<<<dim3(16, KS), 320, 0, stream>>>(c_idx, i_idx, j_idx, mask, pixf, Wfull,
                                                flag, part);
  main_reduce<<<320, 256, 0, stream>>>(part, biasf, (float*)d_out);
}

// Round 6
// 1325.510 us; speedup vs baseline: 1.3927x; 1.3927x over previous
//
#include <hip/hip_runtime.h>

typedef unsigned short u16;
typedef unsigned int   u32;

__device__ __forceinline__ float bf2f(u16 h){ return __uint_as_float(((u32)h)<<16); }
// weight load: bf16 or fp32 selected by runtime flag (wave-uniform branch)
__device__ __forceinline__ float ldw(const void* p, size_t i, int bf){
  return bf ? bf2f(((const u16*)p)[i]) : ((const float*)p)[i];
}

// ---------------- constants ----------------
#define BTASK   2048
#define KTOT    10320      // 6*1720
#define NP      40
#define KS      30         // k-split segments of the main pass
#define SEGLEN  344        // 30*344 = 10320; chunks 5x64 + 24

// ws byte offsets (256-aligned). Peak usage ~11.3 MiB.
#define OFF_PIX  0u          // 36000
#define OFF_WF   36096u      // 1,658,880 (10368 rows x 40 f32; rows >=10320 stay 0)
#define OFF_HR   1694976u    // 288,000
#define OFF_WO   1982976u    // 17,200
#define OFF_RR   2000384u    // 8,000
#define OFF_BF   2008576u    // 160
#define OFF_FLG  2008832u    // 4
#define OFF_O12  2009088u    // 17,200
#define OFF_BCH  2026368u    // 6,400 bias-chain buffers
// transients (all dead before main pass)
#define OFF_S3   2032896u    // 81,920
#define OFF_S2   2114816u    // 163,840
#define OFF_HF   2278656u    // 288,000
#define OFF_R3   2566656u    // 288,000
#define OFF_R2   2854656u    // 960,000
#define OFF_R1   3814656u    // 960,000 (ends 4,774,656)
#define OFF_PART 2032896u    // 9,830,400 (aliases S3..R1; ends 11,863,296)

// bias-chain float indices within OFF_BCH
#define B_BO1  0
#define B_BI1  64
#define B_BN1  384
#define B_BOBJ 896
#define B_BIO  960
#define B_BN2  1280
#define B_BH   1536

// ---------------- dtype detect: point_mask is all-ones by construction
__global__ void detect_kernel(const u32* __restrict__ m, int* __restrict__ flag){
  if (threadIdx.x == 0) flag[0] = (m[0] == 0x3F803F80u) ? 1 : 0;
}

// ---------------- pix[c,i,j] = w0*(wc[c]+bc) + w1*(wx[i]+bx) + w2*(wy[j]+by) + bcomb
__global__ void pix_kernel(const void* wc, const void* bc, const void* wx, const void* bx,
                           const void* wy, const void* by, const void* wcb, const void* bcb,
                           const int* __restrict__ flag, float* __restrict__ pixf){
  int bf = flag[0];
  int e = blockIdx.x*256 + threadIdx.x;
  if (e >= 9000) return;
  int c = e/900, r = e%900, i = r/30, j = r%30;
  float col = ldw(wc,c,bf) + ldw(bc,0,bf);
  float xe  = ldw(wx,i,bf) + ldw(bx,0,bf);
  float ye  = ldw(wy,j,bf) + ldw(by,0,bf);
  pixf[e] = ldw(wcb,0,bf)*col + ldw(wcb,1,bf)*xe + ldw(wcb,2,bf)*ye + ldw(bcb,0,bf);
}

// ---------------- naive GEMM: C[m*N+n] = sum_k A[m*K+k]*B[k*N+n]
template<int AW, int BW>
__global__ void ngemm(const void* __restrict__ A, const void* __restrict__ Bv,
                      float* __restrict__ C, int M, int N, int K,
                      const int* __restrict__ flag){
  int bf = flag[0];
  int oi = blockIdx.x*256 + threadIdx.x;
  if (oi >= M*N) return;
  int m = oi / N, n = oi % N;
  const float* Af = (const float*)A;
  const float* Bf = (const float*)Bv;
  float s = 0.f;
  for (int k = 0; k < K; k++) {
    float a = AW ? ldw(A, (size_t)m*K + k, bf) : Af[(size_t)m*K + k];
    float b = BW ? ldw(Bv, (size_t)k*N + n, bf) : Bf[(size_t)k*N + n];
    s += a*b;
  }
  C[oi] = s;
}

// ---------------- Hresh[j*240 + p*40 + n] = Whead[(p*300+j)*40 + n]
__global__ void repack_kernel(const float* __restrict__ Hfp, float* __restrict__ Hresh){
  int oi = blockIdx.x*256 + threadIdx.x;
  if (oi >= 72000) return;
  int j = oi/240, c = oi%240, p = c/40, n = c%40;
  Hresh[oi] = Hfp[(size_t)(p*300+j)*40 + n];
}

// ---------------- Wfull[k*40+n], k = p*1720+g*86+t:  sum_d wobj[t,d]*R1[(g*50+d)][p*40+n]
__global__ void wfull_kernel(const float* __restrict__ wobj, const float* __restrict__ R1,
                             float* __restrict__ Wfull){
  int oi = blockIdx.x*256 + threadIdx.x;
  if (oi >= KTOT*NP) return;
  int k = oi/NP, n = oi%NP;
  int p = k/1720, r = k%1720, g = r/86, t = r%86;
  float s = 0.f;
  for (int d = 0; d < 50; d++)
    s += wobj[t*50 + d] * R1[(size_t)(g*50+d)*240 + p*40 + n];
  Wfull[oi] = s;
}

// ---------------- r1red[j*40+n] = sum_{g<20,p<6} R1[(g*50+j)][p*40+n]
__global__ void r1red_kernel(const float* __restrict__ R1, float* __restrict__ r1red){
  int oi = blockIdx.x*256 + threadIdx.x;
  if (oi >= 2000) return;
  int j = oi/40, n = oi%40;
  float s = 0.f;
  for (int g = 0; g < 20; g++)
    for (int p = 0; p < 6; p++)
      s += R1[(size_t)(g*50+j)*240 + p*40 + n];
  r1red[oi] = s;
}

// ---------------- parallel bias-chain GEMV: out[n] = b2[n] + sum_k x[k]*W[k*N+n]
// XW: x is a weight vector (dtype per flag) vs fp32 ws buffer.
template<int XW>
__global__ void gemv_kernel(const void* __restrict__ x, const void* __restrict__ W,
                            const void* __restrict__ b2, float* __restrict__ out,
                            int N, int K, const int* __restrict__ flag){
  __shared__ float red[4][64];
  int bf = flag[0];
  int nt = threadIdx.x & 63;
  int kt = threadIdx.x >> 6;
  int n = blockIdx.x*64 + nt;
  float s = 0.f;
  for (int k = kt; k < K; k += 4) {
    float xv = XW ? ldw(x,k,bf) : ((const float*)x)[k];
    float wv = (n < N) ? ldw(W,(size_t)k*N+n,bf) : 0.f;
    s += xv*wv;
  }
  red[kt][nt] = s;
  __syncthreads();
  if (kt == 0 && n < N)
    out[n] = red[0][nt]+red[1][nt]+red[2][nt]+red[3][nt] + ldw(b2,n,bf);
}

// ---------------- final bias combine:
// biasf[n] = bh[n] + sum_j bio[j]*sum_p Hresh[j*240+p*40+n] + sum_j bobj[j]*r1red[j*40+n]
__global__ void biasfin_kernel(const float* __restrict__ bch,
                               const float* __restrict__ Hresh,
                               const float* __restrict__ r1red,
                               float* __restrict__ biasf){
  __shared__ float red[4][64];
  int nt = threadIdx.x & 63;
  int kt = threadIdx.x >> 6;
  int n = nt;
  float s = 0.f;
  if (n < NP) {
    for (int j = kt; j < 300; j += 4) {
      float h = 0.f;
      #pragma unroll
      for (int p = 0; p < 6; p++) h += Hresh[j*240 + p*40 + n];
      s += bch[B_BIO + j] * h;
    }
    for (int j = kt; j < 50; j += 4)
      s += bch[B_BOBJ + j] * r1red[j*40 + n];
  }
  red[kt][nt] = s;
  __syncthreads();
  if (kt == 0 && n < NP)
    biasf[n] = red[0][nt]+red[1][nt]+red[2][nt]+red[3][nt] + bch[B_BH + n];
}

// ---------------- main: gather v = pix[c,i,j]*mask, GEMV vs Wfull, k-split partials
__launch_bounds__(320, 2)
__global__ void main_gather(const int* __restrict__ c_idx, const int* __restrict__ i_idx,
                            const int* __restrict__ j_idx, const void* __restrict__ maskv,
                            const float* __restrict__ pixf, const float* __restrict__ Wfull,
                            const int* __restrict__ flag, float* __restrict__ part){
  __shared__ float pixs[9000];
  __shared__ float vbuf[64*129];   // [k][task], +1 pad breaks bank alignment
  int bf = flag[0];
  const u16*   mh = (const u16*)maskv;
  const float* mf = (const float*)maskv;
  int tid = threadIdx.x;
  for (int e = tid; e < 9000; e += 320) pixs[e] = pixf[e];
  int task0 = blockIdx.x << 7;           // 16 blocks x 128 tasks
  int kseg0 = blockIdx.y * SEGLEN;       // 30 segments x 344
  int lane = tid & 63;
  int ng = __builtin_amdgcn_readfirstlane(tid >> 6);   // wave 0..4 -> 8 output cols
  float acc[2][8] = {};
  __syncthreads();
  for (int cb = 0; cb < 6; cb++) {
    int kc0 = kseg0 + cb*64;
    int kc = (cb == 5) ? 24 : 64;
    int nq = kc >> 2;
    if (kc < 64)
      for (int e = tid; e < (64-kc)*129; e += 320) vbuf[kc*129 + e] = 0.f;
    int totq = nq << 7;
    for (int e4 = tid; e4 < totq; e4 += 320) {
      int t, q;
      if (nq == 16) { t = e4 >> 4; q = e4 & 15; }
      else          { t = (int)((u32)e4 / 6u); q = e4 - t*6; }
      int gk = kc0 + (q << 2);
      size_t gb = (size_t)(task0 + t)*KTOT + gk;
      int4 c4 = *(const int4*)(c_idx + gb);
      int4 i4 = *(const int4*)(i_idx + gb);
      int4 j4 = *(const int4*)(j_idx + gb);
      float mv[4];
      if (bf) {
        ushort4 m4 = *(const ushort4*)(mh + gb);
        mv[0]=bf2f(m4.x); mv[1]=bf2f(m4.y); mv[2]=bf2f(m4.z); mv[3]=bf2f(m4.w);
      } else {
        float4 m4 = *(const float4*)(mf + gb);
        mv[0]=m4.x; mv[1]=m4.y; mv[2]=m4.z; mv[3]=m4.w;
      }
      int cc[4] = {c4.x,c4.y,c4.z,c4.w};
      int ii[4] = {i4.x,i4.y,i4.z,i4.w};
      int jj[4] = {j4.x,j4.y,j4.z,j4.w};
      int kk = q << 2;
      #pragma unroll
      for (int x = 0; x < 4; x++)
        vbuf[(kk+x)*129 + t] = pixs[cc[x]*900 + ii[x]*30 + jj[x]] * mv[x];
    }
    __syncthreads();
    const float* Wk = Wfull + (size_t)kc0*NP + ng*8;
    for (int k = 0; k < 64; k++) {
      float v0 = vbuf[k*129 + 2*lane];
      float v1 = vbuf[k*129 + 2*lane + 1];
      const float* w = Wk + k*NP;
      float wv[8];
      #pragma unroll
      for (int n = 0; n < 8; n++) wv[n] = w[n];
      #pragma unroll
      for (int n = 0; n < 8; n++) { acc[0][n] += v0*wv[n]; acc[1][n] += v1*wv[n]; }
    }
    __syncthreads();
  }
  size_t base = ((size_t)blockIdx.y*BTASK + task0 + (lane<<1))*NP + ng*8;
  #pragma unroll
  for (int i = 0; i < 2; i++) {
    float4 x = { acc[i][0], acc[i][1], acc[i][2], acc[i][3] };
    float4 y = { acc[i][4], acc[i][5], acc[i][6], acc[i][7] };
    *(float4*)(part + base + i*NP)     = x;
    *(float4*)(part + base + i*NP + 4) = y;
  }
}

// ---------------- reduce partials + bias, emit FP32
__global__ void main_reduce(const float* __restrict__ part, const float* __restrict__ biasf,
                            float* __restrict__ out){
  int oi = blockIdx.x*256 + threadIdx.x;
  if (oi >= BTASK*NP) return;
  float s = biasf[oi % NP];
  for (int z = 0; z < KS; z++) s += part[(size_t)z*(BTASK*NP) + oi];
  out[oi] = s;
}

extern "C" void kernel_launch(void* const* d_in, const int* in_sizes, int n_in,
                              void* d_out, int out_size, void* d_ws, size_t ws_size,
                              hipStream_t stream){
  const int* c_idx = (const int*)d_in[0];
  const int* i_idx = (const int*)d_in[1];
  const int* j_idx = (const int*)d_in[2];
  const void* mask = d_in[3];
  const void *w_color=d_in[4], *b_color=d_in[5], *w_x=d_in[6], *b_x=d_in[7];
  const void *w_y=d_in[8], *b_y=d_in[9], *w_comb=d_in[10], *b_comb=d_in[11];
  const void *oW1=d_in[12], *ob1=d_in[13], *oW2=d_in[14], *ob2=d_in[15];
  const void *oW3=d_in[16], *ob3=d_in[17];
  const void *ioW1=d_in[18], *iob1=d_in[19], *ioW2=d_in[20], *iob2=d_in[21];
  const void *ioW3=d_in[22], *iob3=d_in[23];
  const void *nW1=d_in[24], *nb1=d_in[25], *nW2=d_in[26], *nb2=d_in[27];
  const void *nW3=d_in[28], *nb3=d_in[29], *nW4=d_in[30], *nb4=d_in[31];

  char* ws = (char*)d_ws;
  float* pixf  = (float*)(ws + OFF_PIX);
  float* Wfull = (float*)(ws + OFF_WF);
  float* Hresh = (float*)(ws + OFF_HR);
  float* wobj  = (float*)(ws + OFF_WO);
  float* r1red = (float*)(ws + OFF_RR);
  float* biasf = (float*)(ws + OFF_BF);
  int*   flag  = (int*)  (ws + OFF_FLG);
  float* o12   = (float*)(ws + OFF_O12);
  float* bch   = (float*)(ws + OFF_BCH);
  float* S3p   = (float*)(ws + OFF_S3);
  float* S2p   = (float*)(ws + OFF_S2);
  float* Hfp   = (float*)(ws + OFF_HF);
  float* R3p   = (float*)(ws + OFF_R3);
  float* R2p   = (float*)(ws + OFF_R2);
  float* R1p   = (float*)(ws + OFF_R1);
  float* part  = (float*)(ws + OFF_PART);

  detect_kernel<<<1, 64, 0, stream>>>((const u32*)mask, flag);
  // zero Wfull incl pad rows 10320..10367 (read by the 24-wide tail chunks)
  hipMemsetAsync(ws + OFF_WF, 0, (size_t)10368*NP*4, stream);

  pix_kernel<<<36, 256, 0, stream>>>(w_color, b_color, w_x, b_x, w_y, b_y, w_comb, b_comb,
                                     flag, pixf);
  // head chain (right-assoc): S3 = nW3@nW4, S2 = nW2@S3, Whead = nW1@S2
  ngemm<1,1><<<80,  256, 0, stream>>>(nW3, nW4, S3p, 512, 40, 256, flag);
  ngemm<1,0><<<160, 256, 0, stream>>>(nW2, S3p, S2p, 1024, 40, 512, flag);
  ngemm<1,0><<<282, 256, 0, stream>>>(nW1, S2p, Hfp, 1800, 40, 1024, flag);
  repack_kernel<<<282, 256, 0, stream>>>(Hfp, Hresh);
  // io chain: R3 = ioW3@Hresh, R2 = ioW2@R3, R1 = ioW1@R2
  ngemm<1,0><<<282, 256, 0, stream>>>(ioW3, Hresh, R3p, 300, 240, 300, flag);
  ngemm<1,0><<<938, 256, 0, stream>>>(ioW2, R3p, R2p, 1000, 240, 300, flag);
  ngemm<1,0><<<938, 256, 0, stream>>>(ioW1, R2p, R1p, 1000, 240, 1000, flag);
  // obj chain: o12 = oW1@oW2, Wobj = o12@oW3
  ngemm<1,1><<<17, 256, 0, stream>>>(oW1, oW2, o12, 86, 50, 86, flag);
  ngemm<0,1><<<17, 256, 0, stream>>>(o12, oW3, wobj, 86, 50, 50, flag);
  // composed weight
  wfull_kernel<<<1613, 256, 0, stream>>>(wobj, R1p, Wfull);
  r1red_kernel<<<8, 256, 0, stream>>>(R1p, r1red);
  // parallel bias chain
  gemv_kernel<1><<<1, 256, 0, stream>>>(ob1,  oW2, ob2, bch+B_BO1,  50,   86, flag);
  gemv_kernel<1><<<5, 256, 0, stream>>>(iob1, ioW2, iob2, bch+B_BI1, 300, 1000, flag);
  gemv_kernel<1><<<8, 256, 0, stream>>>(nb1,  nW2, nb2, bch+B_BN1, 512, 1024, flag);
  gemv_kernel<0><<<1, 256, 0, stream>>>(bch+B_BO1, oW3, ob3, bch+B_BOBJ,  50,  50, flag);
  gemv_kernel<0><<<5, 256, 0, stream>>>(bch+B_BI1, ioW3, iob3, bch+B_BIO, 300, 300, flag);
  gemv_kernel<0><<<4, 256, 0, stream>>>(bch+B_BN1, nW3, nb3, bch+B_BN2, 256, 512, flag);
  gemv_kernel<0><<<1, 256, 0, stream>>>(bch+B_BN2, nW4, nb4, bch+B_BH,  40, 256, flag);
  biasfin_kernel<<<1, 256, 0, stream>>>(bch, Hresh, r1red, biasf);
  // main pass
  main_gather<<<dim3(16, KS), 320, 0, stream>>>(c_idx, i_idx, j_idx, mask, pixf, Wfull,
                                                flag, part);
  main_reduce<<<320, 256, 0, stream>>>(part, biasf, (float*)d_out);
}

// Round 7
// 828.393 us; speedup vs baseline: 2.2284x; 1.6001x over previous
//
#include <hip/hip_runtime.h>

typedef unsigned short u16;
typedef unsigned int   u32;

__device__ __forceinline__ float bf2f(u16 h){ return __uint_as_float(((u32)h)<<16); }
// weight load: bf16 or fp32 selected by runtime flag (wave-uniform branch)
__device__ __forceinline__ float ldw(const void* p, size_t i, int bf){
  return bf ? bf2f(((const u16*)p)[i]) : ((const float*)p)[i];
}

// ---------------- constants ----------------
#define BTASK   2048
#define KTOT    10320      // 6*1720
#define NP      40
#define KS      30         // k-split segments of the main pass
#define SEGLEN  344        // 30*344 = 10320; chunks 5x64 + 24

// ws byte offsets (256-aligned). Peak usage 11,863,296 B (~11.3 MiB, proven safe).
#define OFF_PIX  0u          // 36000
#define OFF_WF   36096u      // 1,658,880 (10368 rows x 40 f32; rows >=10320 stay 0)
#define OFF_HR   1694976u    // 288,000
#define OFF_WO   1982976u    // 17,200
#define OFF_RR   2000384u    // 8,000
#define OFF_BF   2008576u    // 160
#define OFF_FLG  2008832u    // 4
#define OFF_O12  2009088u    // 17,200
#define OFF_BCH  2026368u    // 6,400 bias-chain buffers
// transient ping-pong regions (3,840,000 B each; all dead before main pass)
#define OFF_P    2032896u    // S3 parts -> Hfp parts -> R2 parts
#define OFF_Q    5872896u    // S2 parts -> R3 parts -> R1 parts
#define OFF_PART 2032896u    // 9,830,400 (aliases P+Q; ends 11,863,296)

// bias-chain float indices within OFF_BCH
#define B_BO1  0
#define B_BI1  64
#define B_BN1  384
#define B_BOBJ 896
#define B_BIO  960
#define B_BN2  1280
#define B_BH   1536

// ---------------- dtype detect: point_mask is all-ones by construction
__global__ void detect_kernel(const u32* __restrict__ m, int* __restrict__ flag){
  if (threadIdx.x == 0) flag[0] = (m[0] == 0x3F803F80u) ? 1 : 0;
}

// ---------------- pix[c,i,j] = w0*(wc[c]+bc) + w1*(wx[i]+bx) + w2*(wy[j]+by) + bcomb
__global__ void pix_kernel(const void* wc, const void* bc, const void* wx, const void* bx,
                           const void* wy, const void* by, const void* wcb, const void* bcb,
                           const int* __restrict__ flag, float* __restrict__ pixf){
  int bf = flag[0];
  int e = blockIdx.x*256 + threadIdx.x;
  if (e >= 9000) return;
  int c = e/900, r = e%900, i = r/30, j = r%30;
  float col = ldw(wc,c,bf) + ldw(bc,0,bf);
  float xe  = ldw(wx,i,bf) + ldw(bx,0,bf);
  float ye  = ldw(wy,j,bf) + ldw(by,0,bf);
  pixf[e] = ldw(wcb,0,bf)*col + ldw(wcb,1,bf)*xe + ldw(wcb,2,bf)*ye + ldw(bcb,0,bf);
}

// ---------------- tiled GEMM, fp32 accum, split-K via gridDim.z, B part-sum folded
// A: [M][K]; AW => weight dtype per flag, else fp32 ws. B: [K][N] likewise (BW),
// with nB parts of stride bStride (fp32 only when nB>1). C: fp32 parts [z][M][N].
template<int AW, int BW>
__launch_bounds__(256)
__global__ void gemm64(const void* __restrict__ A, const void* __restrict__ Bv,
                       float* __restrict__ Cp, int M, int N, int K, int nB, int bStride,
                       const int* __restrict__ flag){
  __shared__ float As[16][68];   // 68*4 = 272 B row stride (16B-aligned)
  __shared__ float Bs[16][68];
  int bf = flag[0];
  const float* Af = (const float*)A;
  const float* Bf = (const float*)Bv;
  int tid = threadIdx.x;
  int m0 = blockIdx.x*64, n0 = blockIdx.y*64;
  int Z = gridDim.z;
  int kc = (K + Z - 1)/Z;
  int k0 = blockIdx.z*kc, k1 = min(K, k0 + kc);
  float acc[4][4] = {};
  int tm = tid & 15, tn = tid >> 4;
  for (int kb = k0; kb < k1; kb += 16) {
    #pragma unroll
    for (int it = 0; it < 4; it++) {
      int idx = tid + it*256;
      { int kk = idx & 15, m = idx >> 4;
        float v = 0.f; int gm = m0+m, gk = kb+kk;
        if (gm < M && gk < k1)
          v = AW ? ldw(A, (size_t)gm*K + gk, bf) : Af[(size_t)gm*K + gk];
        As[kk][m] = v; }
      { int n = idx & 63, kk = idx >> 6;
        float v = 0.f; int gn = n0+n, gk = kb+kk;
        if (gn < N && gk < k1) {
          size_t off = (size_t)gk*N + gn;
          if (BW) v = ldw(Bv, off, bf);
          else for (int s = 0; s < nB; s++) v += Bf[(size_t)s*bStride + off];
        }
        Bs[kk][n] = v; }
    }
    __syncthreads();
    #pragma unroll
    for (int kk = 0; kk < 16; kk++) {
      float4 a4 = *(const float4*)&As[kk][tm*4];
      float4 b4 = *(const float4*)&Bs[kk][tn*4];
      float aa[4] = {a4.x,a4.y,a4.z,a4.w};
      float bb[4] = {b4.x,b4.y,b4.z,b4.w};
      #pragma unroll
      for (int i = 0; i < 4; i++)
        #pragma unroll
        for (int j = 0; j < 4; j++) acc[i][j] += aa[i]*bb[j];
    }
    __syncthreads();
  }
  float* C = Cp + (size_t)blockIdx.z*M*N;
  #pragma unroll
  for (int i = 0; i < 4; i++)
    #pragma unroll
    for (int j = 0; j < 4; j++) {
      int gm = m0 + tm*4 + i, gn = n0 + tn*4 + j;
      if (gm < M && gn < N) C[(size_t)gm*N + gn] = acc[i][j];
    }
}

// ---------------- Hresh[j*240 + p*40 + n] = sum_{s<8} Hfp[s][(p*300+j)*40 + n]
__global__ void repack_kernel(const float* __restrict__ Hfp, float* __restrict__ Hresh){
  int oi = blockIdx.x*256 + threadIdx.x;
  if (oi >= 72000) return;
  int j = oi/240, c = oi%240, p = c/40, n = c%40;
  float s = 0.f;
  #pragma unroll
  for (int sp = 0; sp < 8; sp++) s += Hfp[(size_t)sp*72000 + (p*300+j)*40 + n];
  Hresh[oi] = s;
}

// ---------------- Wfull[k*40+n], k = p*1720+g*86+t: sum_d wobj[t,d]*R1[(g*50+d)][p*40+n]
// R1 folded from 4 parts.
__global__ void wfull_kernel(const float* __restrict__ wobj, const float* __restrict__ R1p,
                             float* __restrict__ Wfull){
  int oi = blockIdx.x*256 + threadIdx.x;
  if (oi >= KTOT*NP) return;
  int k = oi/NP, n = oi%NP;
  int p = k/1720, r = k%1720, g = r/86, t = r%86;
  float s = 0.f;
  for (int d = 0; d < 50; d++) {
    size_t off = (size_t)(g*50+d)*240 + p*40 + n;
    float rv = R1p[off] + R1p[240000+off] + R1p[480000+off] + R1p[720000+off];
    s += wobj[t*50 + d] * rv;
  }
  Wfull[oi] = s;
}

// ---------------- r1red[j*40+n] = sum_{s<4,g<20,p<6} R1p[s][(g*50+j)*240+p*40+n]
__global__ void r1red_kernel(const float* __restrict__ R1p, float* __restrict__ r1red){
  int oi = blockIdx.x*256 + threadIdx.x;
  if (oi >= 2000) return;
  int j = oi/40, n = oi%40;
  float s = 0.f;
  for (int sp = 0; sp < 4; sp++)
    for (int g = 0; g < 20; g++)
      for (int p = 0; p < 6; p++)
        s += R1p[(size_t)sp*240000 + (g*50+j)*240 + p*40 + n];
  r1red[oi] = s;
}

// ---------------- parallel bias-chain GEMV: out[n] = b2[n] + sum_k x[k]*W[k*N+n]
template<int XW>
__global__ void gemv_kernel(const void* __restrict__ x, const void* __restrict__ W,
                            const void* __restrict__ b2, float* __restrict__ out,
                            int N, int K, const int* __restrict__ flag){
  __shared__ float red[4][64];
  int bf = flag[0];
  int nt = threadIdx.x & 63;
  int kt = threadIdx.x >> 6;
  int n = blockIdx.x*64 + nt;
  float s = 0.f;
  for (int k = kt; k < K; k += 4) {
    float xv = XW ? ldw(x,k,bf) : ((const float*)x)[k];
    float wv = (n < N) ? ldw(W,(size_t)k*N+n,bf) : 0.f;
    s += xv*wv;
  }
  red[kt][nt] = s;
  __syncthreads();
  if (kt == 0 && n < N)
    out[n] = red[0][nt]+red[1][nt]+red[2][nt]+red[3][nt] + ldw(b2,n,bf);
}

// ---------------- final bias combine
__global__ void biasfin_kernel(const float* __restrict__ bch,
                               const float* __restrict__ Hresh,
                               const float* __restrict__ r1red,
                               float* __restrict__ biasf){
  __shared__ float red[4][64];
  int nt = threadIdx.x & 63;
  int kt = threadIdx.x >> 6;
  int n = nt;
  float s = 0.f;
  if (n < NP) {
    for (int j = kt; j < 300; j += 4) {
      float h = 0.f;
      #pragma unroll
      for (int p = 0; p < 6; p++) h += Hresh[j*240 + p*40 + n];
      s += bch[B_BIO + j] * h;
    }
    for (int j = kt; j < 50; j += 4)
      s += bch[B_BOBJ + j] * r1red[j*40 + n];
  }
  red[kt][nt] = s;
  __syncthreads();
  if (kt == 0 && n < NP)
    biasf[n] = red[0][nt]+red[1][nt]+red[2][nt]+red[3][nt] + bch[B_BH + n];
}

// ---------------- main: gather v = pix[c,i,j]*mask, GEMV vs Wfull, k-split partials
__launch_bounds__(320, 2)
__global__ void main_gather(const int* __restrict__ c_idx, const int* __restrict__ i_idx,
                            const int* __restrict__ j_idx, const void* __restrict__ maskv,
                            const float* __restrict__ pixf, const float* __restrict__ Wfull,
                            const int* __restrict__ flag, float* __restrict__ part){
  __shared__ float pixs[9000];
  __shared__ float vbuf[64*129];   // [k][task], +1 pad breaks bank alignment
  int bf = flag[0];
  const u16*   mh = (const u16*)maskv;
  const float* mf = (const float*)maskv;
  int tid = threadIdx.x;
  for (int e = tid; e < 9000; e += 320) pixs[e] = pixf[e];
  int task0 = blockIdx.x << 7;           // 16 blocks x 128 tasks
  int kseg0 = blockIdx.y * SEGLEN;       // 30 segments x 344
  int lane = tid & 63;
  int ng = __builtin_amdgcn_readfirstlane(tid >> 6);   // wave 0..4 -> 8 output cols
  float acc[2][8] = {};
  __syncthreads();
  for (int cb = 0; cb < 6; cb++) {
    int kc0 = kseg0 + cb*64;
    int kc = (cb == 5) ? 24 : 64;
    int nq = kc >> 2;
    if (kc < 64)
      for (int e = tid; e < (64-kc)*129; e += 320) vbuf[kc*129 + e] = 0.f;
    int totq = nq << 7;
    for (int e4 = tid; e4 < totq; e4 += 320) {
      int t, q;
      if (nq == 16) { t = e4 >> 4; q = e4 & 15; }
      else          { t = (int)((u32)e4 / 6u); q = e4 - t*6; }
      int gk = kc0 + (q << 2);
      size_t gb = (size_t)(task0 + t)*KTOT + gk;
      int4 c4 = *(const int4*)(c_idx + gb);
      int4 i4 = *(const int4*)(i_idx + gb);
      int4 j4 = *(const int4*)(j_idx + gb);
      float mv[4];
      if (bf) {
        ushort4 m4 = *(const ushort4*)(mh + gb);
        mv[0]=bf2f(m4.x); mv[1]=bf2f(m4.y); mv[2]=bf2f(m4.z); mv[3]=bf2f(m4.w);
      } else {
        float4 m4 = *(const float4*)(mf + gb);
        mv[0]=m4.x; mv[1]=m4.y; mv[2]=m4.z; mv[3]=m4.w;
      }
      int cc[4] = {c4.x,c4.y,c4.z,c4.w};
      int ii[4] = {i4.x,i4.y,i4.z,i4.w};
      int jj[4] = {j4.x,j4.y,j4.z,j4.w};
      int kk = q << 2;
      #pragma unroll
      for (int x = 0; x < 4; x++)
        vbuf[(kk+x)*129 + t] = pixs[cc[x]*900 + ii[x]*30 + jj[x]] * mv[x];
    }
    __syncthreads();
    const float* Wk = Wfull + (size_t)kc0*NP + ng*8;
    for (int k = 0; k < 64; k++) {
      float v0 = vbuf[k*129 + 2*lane];
      float v1 = vbuf[k*129 + 2*lane + 1];
      const float* w = Wk + k*NP;
      float wv[8];
      #pragma unroll
      for (int n = 0; n < 8; n++) wv[n] = w[n];
      #pragma unroll
      for (int n = 0; n < 8; n++) { acc[0][n] += v0*wv[n]; acc[1][n] += v1*wv[n]; }
    }
    __syncthreads();
  }
  size_t base = ((size_t)blockIdx.y*BTASK + task0 + (lane<<1))*NP + ng*8;
  #pragma unroll
  for (int i = 0; i < 2; i++) {
    float4 x = { acc[i][0], acc[i][1], acc[i][2], acc[i][3] };
    float4 y = { acc[i][4], acc[i][5], acc[i][6], acc[i][7] };
    *(float4*)(part + base + i*NP)     = x;
    *(float4*)(part + base + i*NP + 4) = y;
  }
}

// ---------------- reduce partials + bias, emit FP32
__global__ void main_reduce(const float* __restrict__ part, const float* __restrict__ biasf,
                            float* __restrict__ out){
  int oi = blockIdx.x*256 + threadIdx.x;
  if (oi >= BTASK*NP) return;
  float s = biasf[oi % NP];
  for (int z = 0; z < KS; z++) s += part[(size_t)z*(BTASK*NP) + oi];
  out[oi] = s;
}

extern "C" void kernel_launch(void* const* d_in, const int* in_sizes, int n_in,
                              void* d_out, int out_size, void* d_ws, size_t ws_size,
                              hipStream_t stream){
  const int* c_idx = (const int*)d_in[0];
  const int* i_idx = (const int*)d_in[1];
  const int* j_idx = (const int*)d_in[2];
  const void* mask = d_in[3];
  const void *w_color=d_in[4], *b_color=d_in[5], *w_x=d_in[6], *b_x=d_in[7];
  const void *w_y=d_in[8], *b_y=d_in[9], *w_comb=d_in[10], *b_comb=d_in[11];
  const void *oW1=d_in[12], *ob1=d_in[13], *oW2=d_in[14], *ob2=d_in[15];
  const void *oW3=d_in[16], *ob3=d_in[17];
  const void *ioW1=d_in[18], *iob1=d_in[19], *ioW2=d_in[20], *iob2=d_in[21];
  const void *ioW3=d_in[22], *iob3=d_in[23];
  const void *nW1=d_in[24], *nb1=d_in[25], *nW2=d_in[26], *nb2=d_in[27];
  const void *nW3=d_in[28], *nb3=d_in[29], *nW4=d_in[30], *nb4=d_in[31];

  char* ws = (char*)d_ws;
  float* pixf  = (float*)(ws + OFF_PIX);
  float* Wfull = (float*)(ws + OFF_WF);
  float* Hresh = (float*)(ws + OFF_HR);
  float* wobj  = (float*)(ws + OFF_WO);
  float* r1red = (float*)(ws + OFF_RR);
  float* biasf = (float*)(ws + OFF_BF);
  int*   flag  = (int*)  (ws + OFF_FLG);
  float* o12   = (float*)(ws + OFF_O12);
  float* bch   = (float*)(ws + OFF_BCH);
  float* P     = (float*)(ws + OFF_P);
  float* Q     = (float*)(ws + OFF_Q);
  float* part  = (float*)(ws + OFF_PART);

  detect_kernel<<<1, 64, 0, stream>>>((const u32*)mask, flag);
  // zero Wfull incl pad rows 10320..10367 (read by the 24-wide tail chunks)
  hipMemsetAsync(ws + OFF_WF, 0, (size_t)10368*NP*4, stream);

  pix_kernel<<<36, 256, 0, stream>>>(w_color, b_color, w_x, b_x, w_y, b_y, w_comb, b_comb,
                                     flag, pixf);
  // head chain (right-assoc, split-K parts): S3=nW3@nW4 -> P, S2=nW2@S3 -> Q, Hfp=nW1@S2 -> P
  gemm64<1,1><<<dim3(8,1,8),  256, 0, stream>>>(nW3, nW4, P, 512, 40, 256, 1, 0, flag);
  gemm64<1,0><<<dim3(16,1,8), 256, 0, stream>>>(nW2, P, Q, 1024, 40, 512, 8, 512*40, flag);
  gemm64<1,0><<<dim3(29,1,8), 256, 0, stream>>>(nW1, Q, P, 1800, 40, 1024, 8, 1024*40, flag);
  repack_kernel<<<282, 256, 0, stream>>>(P, Hresh);
  // io chain: R3=ioW3@Hresh -> Q, R2=ioW2@R3 -> P, R1=ioW1@R2 -> Q
  gemm64<1,0><<<dim3(5,4,4),  256, 0, stream>>>(ioW3, Hresh, Q, 300, 240, 300, 1, 0, flag);
  gemm64<1,0><<<dim3(16,4,4), 256, 0, stream>>>(ioW2, Q, P, 1000, 240, 300, 4, 300*240, flag);
  gemm64<1,0><<<dim3(16,4,4), 256, 0, stream>>>(ioW1, P, Q, 1000, 240, 1000, 4, 1000*240, flag);
  // obj chain: o12 = oW1@oW2, Wobj = o12@oW3
  gemm64<1,1><<<dim3(2,1,1),  256, 0, stream>>>(oW1, oW2, o12, 86, 50, 86, 1, 0, flag);
  gemm64<0,1><<<dim3(2,1,1),  256, 0, stream>>>(o12, oW3, wobj, 86, 50, 50, 1, 0, flag);
  // composed weight (folds R1 parts in Q)
  wfull_kernel<<<1613, 256, 0, stream>>>(wobj, Q, Wfull);
  r1red_kernel<<<8, 256, 0, stream>>>(Q, r1red);
  // parallel bias chain
  gemv_kernel<1><<<1, 256, 0, stream>>>(ob1,  oW2, ob2, bch+B_BO1,  50,   86, flag);
  gemv_kernel<1><<<5, 256, 0, stream>>>(iob1, ioW2, iob2, bch+B_BI1, 300, 1000, flag);
  gemv_kernel<1><<<8, 256, 0, stream>>>(nb1,  nW2, nb2, bch+B_BN1, 512, 1024, flag);
  gemv_kernel<0><<<1, 256, 0, stream>>>(bch+B_BO1, oW3, ob3, bch+B_BOBJ,  50,  50, flag);
  gemv_kernel<0><<<5, 256, 0, stream>>>(bch+B_BI1, ioW3, iob3, bch+B_BIO, 300, 300, flag);
  gemv_kernel<0><<<4, 256, 0, stream>>>(bch+B_BN1, nW3, nb3, bch+B_BN2, 256, 512, flag);
  gemv_kernel<0><<<1, 256, 0, stream>>>(bch+B_BN2, nW4, nb4, bch+B_BH,  40, 256, flag);
  biasfin_kernel<<<1, 256, 0, stream>>>(bch, Hresh, r1red, biasf);
  // main pass
  main_gather<<<dim3(16, KS), 320, 0, stream>>>(c_idx, i_idx, j_idx, mask, pixf, Wfull,
                                                flag, part);
  main_reduce<<<320, 256, 0, stream>>>(part, biasf, (float*)d_out);
}

// Round 8
// 513.742 us; speedup vs baseline: 3.5933x; 1.6125x over previous
//
#include <hip/hip_runtime.h>

typedef unsigned short u16;
typedef unsigned int   u32;

__device__ __forceinline__ float bf2f(u16 h){ return __uint_as_float(((u32)h)<<16); }
// weight load: bf16 or fp32 selected by runtime flag (wave-uniform branch)
__device__ __forceinline__ float ldw(const void* p, size_t i, int bf){
  return bf ? bf2f(((const u16*)p)[i]) : ((const float*)p)[i];
}

// ---------------- constants ----------------
#define BTASK   2048
#define KTOT    10320      // 6*1720
#define NP      40
#define KS      30         // k-split segments of the main pass
#define SEGLEN  344        // 30*344 = 10320; chunks 5x64 + 24

// ws byte offsets (256-aligned). Peak usage ~11.3 MiB (proven safe).
#define OFF_TBL  0u          // 288 (70-float pix table)
#define OFF_WF   36096u      // 1,651,200 (10320 rows x 40 f32)
#define OFF_HR   1694976u    // 288,000
#define OFF_WO   1982976u    // 17,200
#define OFF_RR   2000384u    // 8,000
#define OFF_BF   2008576u    // 160
#define OFF_FLG  2008832u    // 4
#define OFF_O12  2009088u    // 17,200
#define OFF_BCH  2026368u    // 6,400 bias-chain buffers
// transient ping-pong regions (3,840,000 B each; all dead before main pass)
#define OFF_P    2032896u    // S3 parts -> Hfp parts -> R2 parts
#define OFF_Q    5872896u    // S2 parts -> R3 parts -> R1 parts
#define OFF_PART 2032896u    // 9,830,400 (aliases P+Q; ends 11,863,296)

// bias-chain float indices within OFF_BCH
#define B_BO1  0
#define B_BI1  64
#define B_BN1  384
#define B_BOBJ 896
#define B_BIO  960
#define B_BN2  1280
#define B_BH   1536

// ---------------- dtype detect: point_mask is all-ones by construction
__global__ void detect_kernel(const u32* __restrict__ m, int* __restrict__ flag){
  if (threadIdx.x == 0) flag[0] = (m[0] == 0x3F803F80u) ? 1 : 0;
}

// ---------------- pix table, decomposed: pix[c,i,j] = tbl[c] + tbl[10+i] + tbl[40+j]
// tbl[c]    = w0*(wc[c]+bc) + bcomb
// tbl[10+i] = w1*(wx[i]+bx)
// tbl[40+j] = w2*(wy[j]+by)
__global__ void table_kernel(const void* wc, const void* bc, const void* wx, const void* bx,
                             const void* wy, const void* by, const void* wcb, const void* bcb,
                             const int* __restrict__ flag, float* __restrict__ tbl){
  int bf = flag[0];
  int e = threadIdx.x;
  if (e < 10)      tbl[e] = ldw(wcb,0,bf)*(ldw(wc,e,bf)+ldw(bc,0,bf)) + ldw(bcb,0,bf);
  else if (e < 40) tbl[e] = ldw(wcb,1,bf)*(ldw(wx,e-10,bf)+ldw(bx,0,bf));
  else if (e < 70) tbl[e] = ldw(wcb,2,bf)*(ldw(wy,e-40,bf)+ldw(by,0,bf));
}

// ---------------- tiled GEMM, fp32 accum, split-K via gridDim.z, B part-sum folded
template<int AW, int BW>
__launch_bounds__(256)
__global__ void gemm64(const void* __restrict__ A, const void* __restrict__ Bv,
                       float* __restrict__ Cp, int M, int N, int K, int nB, int bStride,
                       const int* __restrict__ flag){
  __shared__ float As[16][68];
  __shared__ float Bs[16][68];
  int bf = flag[0];
  const float* Af = (const float*)A;
  const float* Bf = (const float*)Bv;
  int tid = threadIdx.x;
  int m0 = blockIdx.x*64, n0 = blockIdx.y*64;
  int Z = gridDim.z;
  int kc = (K + Z - 1)/Z;
  int k0 = blockIdx.z*kc, k1 = min(K, k0 + kc);
  float acc[4][4] = {};
  int tm = tid & 15, tn = tid >> 4;
  for (int kb = k0; kb < k1; kb += 16) {
    #pragma unroll
    for (int it = 0; it < 4; it++) {
      int idx = tid + it*256;
      { int kk = idx & 15, m = idx >> 4;
        float v = 0.f; int gm = m0+m, gk = kb+kk;
        if (gm < M && gk < k1)
          v = AW ? ldw(A, (size_t)gm*K + gk, bf) : Af[(size_t)gm*K + gk];
        As[kk][m] = v; }
      { int n = idx & 63, kk = idx >> 6;
        float v = 0.f; int gn = n0+n, gk = kb+kk;
        if (gn < N && gk < k1) {
          size_t off = (size_t)gk*N + gn;
          if (BW) v = ldw(Bv, off, bf);
          else for (int s = 0; s < nB; s++) v += Bf[(size_t)s*bStride + off];
        }
        Bs[kk][n] = v; }
    }
    __syncthreads();
    #pragma unroll
    for (int kk = 0; kk < 16; kk++) {
      float4 a4 = *(const float4*)&As[kk][tm*4];
      float4 b4 = *(const float4*)&Bs[kk][tn*4];
      float aa[4] = {a4.x,a4.y,a4.z,a4.w};
      float bb[4] = {b4.x,b4.y,b4.z,b4.w};
      #pragma unroll
      for (int i = 0; i < 4; i++)
        #pragma unroll
        for (int j = 0; j < 4; j++) acc[i][j] += aa[i]*bb[j];
    }
    __syncthreads();
  }
  float* C = Cp + (size_t)blockIdx.z*M*N;
  #pragma unroll
  for (int i = 0; i < 4; i++)
    #pragma unroll
    for (int j = 0; j < 4; j++) {
      int gm = m0 + tm*4 + i, gn = n0 + tn*4 + j;
      if (gm < M && gn < N) C[(size_t)gm*N + gn] = acc[i][j];
    }
}

// ---------------- Hresh[j*240 + p*40 + n] = sum_{s<8} Hfp[s][(p*300+j)*40 + n]
__global__ void repack_kernel(const float* __restrict__ Hfp, float* __restrict__ Hresh){
  int oi = blockIdx.x*256 + threadIdx.x;
  if (oi >= 72000) return;
  int j = oi/240, c = oi%240, p = c/40, n = c%40;
  float s = 0.f;
  #pragma unroll
  for (int sp = 0; sp < 8; sp++) s += Hfp[(size_t)sp*72000 + (p*300+j)*40 + n];
  Hresh[oi] = s;
}

// ---------------- Wfull[k*40+n], k = p*1720+g*86+t: sum_d wobj[t,d]*R1[(g*50+d)][p*40+n]
__global__ void wfull_kernel(const float* __restrict__ wobj, const float* __restrict__ R1p,
                             float* __restrict__ Wfull){
  int oi = blockIdx.x*256 + threadIdx.x;
  if (oi >= KTOT*NP) return;
  int k = oi/NP, n = oi%NP;
  int p = k/1720, r = k%1720, g = r/86, t = r%86;
  float s = 0.f;
  #pragma unroll 2
  for (int d = 0; d < 50; d++) {
    size_t off = (size_t)(g*50+d)*240 + p*40 + n;
    float rv = R1p[off] + R1p[240000+off] + R1p[480000+off] + R1p[720000+off];
    s += wobj[t*50 + d] * rv;
  }
  Wfull[oi] = s;
}

// ---------------- r1red[j*40+n] = sum over 480 terms (4 parts x 20 g x 6 p), 8-way reduce
__global__ void r1red_kernel(const float* __restrict__ R1p, float* __restrict__ r1red){
  __shared__ float red[8][33];
  int nt = threadIdx.x & 31, rt = threadIdx.x >> 5;   // 32 outputs x 8 reducers
  int oi = blockIdx.x*32 + nt;
  int j = (oi < 2000) ? oi/40 : 0, n = (oi < 2000) ? oi%40 : 0;
  float s = 0.f;
  if (oi < 2000) {
    #pragma unroll 2
    for (int u = rt; u < 480; u += 8) {
      int sp = u/120, rm = u - sp*120, g = rm/6, p = rm - g*6;
      s += R1p[(size_t)sp*240000 + (g*50+j)*240 + p*40 + n];
    }
  }
  red[rt][nt] = s;
  __syncthreads();
  if (rt < 4) red[rt][nt] += red[rt+4][nt];
  __syncthreads();
  if (rt < 2) red[rt][nt] += red[rt+2][nt];
  __syncthreads();
  if (rt == 0 && oi < 2000) r1red[oi] = red[0][nt] + red[1][nt];
}

// ---------------- merged 3-job GEMV: out[n] = b2[n] + sum_k x[k]*W[k*N+n]
// 256 thr = 16 k-lanes x 16 n-lanes; W always weight dtype; x per-job (xw).
__global__ void gemv3_kernel(
    const void* x0, const void* W0, const void* b0, float* o0, int N0, int K0, int xw0,
    const void* x1, const void* W1, const void* b1, float* o1, int N1, int K1, int xw1,
    const void* x2, const void* W2, const void* b2, float* o2, int N2, int K2, int xw2,
    int s1, int s2, const int* __restrict__ flag){
  __shared__ float red[16][17];
  int bf = flag[0];
  int b = blockIdx.x;
  const void *x, *W, *bb; float* o; int N, K, xw, lb;
  if (b < s1)      { x=x0; W=W0; bb=b0; o=o0; N=N0; K=K0; xw=xw0; lb=b; }
  else if (b < s2) { x=x1; W=W1; bb=b1; o=o1; N=N1; K=K1; xw=xw1; lb=b-s1; }
  else             { x=x2; W=W2; bb=b2; o=o2; N=N2; K=K2; xw=xw2; lb=b-s2; }
  int nt = threadIdx.x & 15, kt = threadIdx.x >> 4;
  int n = lb*16 + nt;
  float s = 0.f;
  if (n < N) {
    #pragma unroll 4
    for (int k = kt; k < K; k += 16) {
      float xv = xw ? ldw(x,k,bf) : ((const float*)x)[k];
      s += xv * ldw(W,(size_t)k*N+n,bf);
    }
  }
  red[kt][nt] = s;
  __syncthreads();
  for (int st = 8; st > 0; st >>= 1) {
    if (kt < st) red[kt][nt] += red[kt+st][nt];
    __syncthreads();
  }
  if (kt == 0 && n < N) o[n] = red[0][nt] + ldw(bb,n,bf);
}

// ---------------- final bias combine
__global__ void biasfin_kernel(const float* __restrict__ bch,
                               const float* __restrict__ Hresh,
                               const float* __restrict__ r1red,
                               float* __restrict__ biasf){
  __shared__ float red[4][64];
  int nt = threadIdx.x & 63;
  int kt = threadIdx.x >> 6;
  int n = nt;
  float s = 0.f;
  if (n < NP) {
    for (int j = kt; j < 300; j += 4) {
      float h = 0.f;
      #pragma unroll
      for (int p = 0; p < 6; p++) h += Hresh[j*240 + p*40 + n];
      s += bch[B_BIO + j] * h;
    }
    for (int j = kt; j < 50; j += 4)
      s += bch[B_BOBJ + j] * r1red[j*40 + n];
  }
  red[kt][nt] = s;
  __syncthreads();
  if (kt == 0 && n < NP)
    biasf[n] = red[0][nt]+red[1][nt]+red[2][nt]+red[3][nt] + bch[B_BH + n];
}

// ---------------- gather one int4-quad into vbuf
__device__ __forceinline__ void gquad(int t, int q, int kc0, int task0,
    const int* __restrict__ c_idx, const int* __restrict__ i_idx,
    const int* __restrict__ j_idx, const void* __restrict__ maskv, int bf,
    const float* __restrict__ tbl, float* __restrict__ vbuf){
  int gk = kc0 + (q << 2);
  size_t gb = (size_t)(task0 + t)*KTOT + gk;
  int4 c4 = *(const int4*)(c_idx + gb);
  int4 i4 = *(const int4*)(i_idx + gb);
  int4 j4 = *(const int4*)(j_idx + gb);
  float mv[4];
  if (bf) {
    ushort4 m4 = *(const ushort4*)((const u16*)maskv + gb);
    mv[0]=bf2f(m4.x); mv[1]=bf2f(m4.y); mv[2]=bf2f(m4.z); mv[3]=bf2f(m4.w);
  } else {
    float4 m4 = *(const float4*)((const float*)maskv + gb);
    mv[0]=m4.x; mv[1]=m4.y; mv[2]=m4.z; mv[3]=m4.w;
  }
  int cc[4]={c4.x,c4.y,c4.z,c4.w}, ii[4]={i4.x,i4.y,i4.z,i4.w}, jj[4]={j4.x,j4.y,j4.z,j4.w};
  int kk = q << 2;
  #pragma unroll
  for (int x = 0; x < 4; x++)
    vbuf[(kk+x)*65 + t] = (tbl[cc[x]] + tbl[10+ii[x]] + tbl[40+jj[x]]) * mv[x];
}

// ---------------- main: gather v, GEMV vs Wfull, k-split partials [seg][col][task]
__launch_bounds__(256, 4)
__global__ void main_gather(const int* __restrict__ c_idx, const int* __restrict__ i_idx,
                            const int* __restrict__ j_idx, const void* __restrict__ maskv,
                            const float* __restrict__ tblg, const float* __restrict__ Wfull,
                            const int* __restrict__ flag, float* __restrict__ part){
  __shared__ float tbl[72];
  __shared__ float vbuf[64*65];    // [k][task], 65 stride: bank-friendly
  int bf = flag[0];
  int tid = threadIdx.x;
  if (tid < 70) tbl[tid] = tblg[tid];
  int task0 = blockIdx.x << 6;            // 32 blocks x 64 tasks
  int kseg0 = blockIdx.y * SEGLEN;        // 30 segments x 344
  int lane = tid & 63;                    // task within block
  int ngbase = __builtin_amdgcn_readfirstlane(tid >> 6) * 10;  // wave -> 10 cols
  float acc[10] = {};
  __syncthreads();
  for (int cb = 0; cb < 6; cb++) {
    int kc0 = kseg0 + cb*64;
    int kc = (cb == 5) ? 24 : 64;
    if (kc == 64) {
      #pragma unroll
      for (int it = 0; it < 4; it++) {
        int e4 = tid + it*256;
        gquad(e4 >> 4, e4 & 15, kc0, task0, c_idx, i_idx, j_idx, maskv, bf, tbl, vbuf);
      }
    } else {
      for (int e4 = tid; e4 < 384; e4 += 256) {
        int t = (int)((u32)e4 / 6u);
        gquad(t, e4 - t*6, kc0, task0, c_idx, i_idx, j_idx, maskv, bf, tbl, vbuf);
      }
    }
    __syncthreads();
    const float* Wk = Wfull + (size_t)kc0*NP + ngbase;
    for (int k = 0; k < kc; k++) {
      float v = vbuf[k*65 + lane];
      const float* wr = Wk + k*NP;
      #pragma unroll
      for (int n = 0; n < 10; n++) acc[n] += v * wr[n];
    }
    __syncthreads();
  }
  // part[seg][col][task] -- coalesced stores
  size_t base = ((size_t)blockIdx.y*NP + ngbase)*BTASK + task0 + lane;
  #pragma unroll
  for (int n = 0; n < 10; n++) part[base + (size_t)n*BTASK] = acc[n];
}

// ---------------- reduce partials + bias, emit FP32; coalesced part reads
__global__ void main_reduce(const float* __restrict__ part, const float* __restrict__ biasf,
                            float* __restrict__ out){
  int id = blockIdx.x*256 + threadIdx.x;      // id = col*2048 + task
  if (id >= BTASK*NP) return;
  int col = id >> 11, t = id & 2047;
  float s = biasf[col];
  #pragma unroll
  for (int z = 0; z < KS; z++) s += part[((size_t)z*NP + col)*BTASK + t];
  out[t*NP + col] = s;
}

extern "C" void kernel_launch(void* const* d_in, const int* in_sizes, int n_in,
                              void* d_out, int out_size, void* d_ws, size_t ws_size,
                              hipStream_t stream){
  const int* c_idx = (const int*)d_in[0];
  const int* i_idx = (const int*)d_in[1];
  const int* j_idx = (const int*)d_in[2];
  const void* mask = d_in[3];
  const void *w_color=d_in[4], *b_color=d_in[5], *w_x=d_in[6], *b_x=d_in[7];
  const void *w_y=d_in[8], *b_y=d_in[9], *w_comb=d_in[10], *b_comb=d_in[11];
  const void *oW1=d_in[12], *ob1=d_in[13], *oW2=d_in[14], *ob2=d_in[15];
  const void *oW3=d_in[16], *ob3=d_in[17];
  const void *ioW1=d_in[18], *iob1=d_in[19], *ioW2=d_in[20], *iob2=d_in[21];
  const void *ioW3=d_in[22], *iob3=d_in[23];
  const void *nW1=d_in[24], *nb1=d_in[25], *nW2=d_in[26], *nb2=d_in[27];
  const void *nW3=d_in[28], *nb3=d_in[29], *nW4=d_in[30], *nb4=d_in[31];

  char* ws = (char*)d_ws;
  float* tblw  = (float*)(ws + OFF_TBL);
  float* Wfull = (float*)(ws + OFF_WF);
  float* Hresh = (float*)(ws + OFF_HR);
  float* wobj  = (float*)(ws + OFF_WO);
  float* r1red = (float*)(ws + OFF_RR);
  float* biasf = (float*)(ws + OFF_BF);
  int*   flag  = (int*)  (ws + OFF_FLG);
  float* o12   = (float*)(ws + OFF_O12);
  float* bch   = (float*)(ws + OFF_BCH);
  float* P     = (float*)(ws + OFF_P);
  float* Q     = (float*)(ws + OFF_Q);
  float* part  = (float*)(ws + OFF_PART);

  detect_kernel<<<1, 64, 0, stream>>>((const u32*)mask, flag);
  table_kernel<<<1, 128, 0, stream>>>(w_color, b_color, w_x, b_x, w_y, b_y,
                                      w_comb, b_comb, flag, tblw);
  // head chain (right-assoc, split-K parts): S3=nW3@nW4 -> P, S2=nW2@S3 -> Q, Hfp=nW1@S2 -> P
  gemm64<1,1><<<dim3(8,1,8),  256, 0, stream>>>(nW3, nW4, P, 512, 40, 256, 1, 0, flag);
  gemm64<1,0><<<dim3(16,1,8), 256, 0, stream>>>(nW2, P, Q, 1024, 40, 512, 8, 512*40, flag);
  gemm64<1,0><<<dim3(29,1,8), 256, 0, stream>>>(nW1, Q, P, 1800, 40, 1024, 8, 1024*40, flag);
  repack_kernel<<<282, 256, 0, stream>>>(P, Hresh);
  // io chain: R3=ioW3@Hresh -> Q, R2=ioW2@R3 -> P, R1=ioW1@R2 -> Q
  gemm64<1,0><<<dim3(5,4,4),  256, 0, stream>>>(ioW3, Hresh, Q, 300, 240, 300, 1, 0, flag);
  gemm64<1,0><<<dim3(16,4,4), 256, 0, stream>>>(ioW2, Q, P, 1000, 240, 300, 4, 300*240, flag);
  gemm64<1,0><<<dim3(16,4,4), 256, 0, stream>>>(ioW1, P, Q, 1000, 240, 1000, 4, 1000*240, flag);
  // obj chain: o12 = oW1@oW2, Wobj = o12@oW3
  gemm64<1,1><<<dim3(2,1,1),  256, 0, stream>>>(oW1, oW2, o12, 86, 50, 86, 1, 0, flag);
  gemm64<0,1><<<dim3(2,1,1),  256, 0, stream>>>(o12, oW3, wobj, 86, 50, 50, 1, 0, flag);
  // composed weight (folds R1 parts in Q)
  wfull_kernel<<<1613, 256, 0, stream>>>(wobj, Q, Wfull);
  r1red_kernel<<<63, 256, 0, stream>>>(Q, r1red);
  // bias chain: 3 merged levels
  gemv3_kernel<<<55, 256, 0, stream>>>(
      ob1,  oW2,  ob2,  bch+B_BO1,  50,   86, 1,
      iob1, ioW2, iob2, bch+B_BI1, 300, 1000, 1,
      nb1,  nW2,  nb2,  bch+B_BN1, 512, 1024, 1,
      4, 23, flag);
  gemv3_kernel<<<39, 256, 0, stream>>>(
      bch+B_BO1, oW3,  ob3,  bch+B_BOBJ,  50,  50, 0,
      bch+B_BI1, ioW3, iob3, bch+B_BIO,  300, 300, 0,
      bch+B_BN1, nW3,  nb3,  bch+B_BN2,  256, 512, 0,
      4, 23, flag);
  gemv3_kernel<<<3, 256, 0, stream>>>(
      bch+B_BN2, nW4, nb4, bch+B_BH, 40, 256, 0,
      bch+B_BN2, nW4, nb4, bch+B_BH, 40, 256, 0,
      bch+B_BN2, nW4, nb4, bch+B_BH, 40, 256, 0,
      3, 3, flag);
  biasfin_kernel<<<1, 256, 0, stream>>>(bch, Hresh, r1red, biasf);
  // main pass
  main_gather<<<dim3(32, KS), 256, 0, stream>>>(c_idx, i_idx, j_idx, mask, tblw, Wfull,
                                                flag, part);
  main_reduce<<<320, 256, 0, stream>>>(part, biasf, (float*)d_out);
}

// Round 9
// 382.588 us; speedup vs baseline: 4.8251x; 1.3428x over previous
//
#include <hip/hip_runtime.h>

typedef unsigned short u16;
typedef unsigned int   u32;

__device__ __forceinline__ float bf2f(u16 h){ return __uint_as_float(((u32)h)<<16); }
// weight load: bf16 or fp32 selected by runtime flag (wave-uniform branch)
__device__ __forceinline__ float ldw(const void* p, size_t i, int bf){
  return bf ? bf2f(((const u16*)p)[i]) : ((const float*)p)[i];
}

// ---------------- constants ----------------
#define BTASK   2048
#define KTOT    10320      // 6*1720
#define NP      40
#define KS      30         // k-split segments of the main pass
#define SEGLEN  344        // 30*344 = 10320; chunks 5x64 + 24

// ws byte offsets (256-aligned). Peak usage ~11.3 MiB (proven safe).
#define OFF_TBL  0u          // 288 (70-float pix table)
#define OFF_WF   36096u      // 1,651,200 (10320 rows x 40 f32)
#define OFF_HR   1694976u    // 288,000
#define OFF_WO   1982976u    // 17,200
#define OFF_RR   2000384u    // 8,000
#define OFF_BF   2008576u    // 160
#define OFF_FLG  2008832u    // 4
#define OFF_O12  2009088u    // 17,200
#define OFF_BCH  2026368u    // 6,400 bias-chain buffers
// transient ping-pong regions (3,840,000 B each; all dead before main pass)
#define OFF_P    2032896u    // S3 parts -> Hfp parts -> R2 parts
#define OFF_Q    5872896u    // S2 parts -> R3 parts -> R1 parts
#define OFF_PART 2032896u    // 9,830,400 (aliases P+Q; ends 11,863,296)

// bias-chain float indices within OFF_BCH
#define B_BO1  0
#define B_BI1  64
#define B_BN1  384
#define B_BOBJ 896
#define B_BIO  960
#define B_BN2  1280
#define B_BH   1536

// ---------------- pix table (+dtype detect merged): pix[c,i,j] = tbl[c]+tbl[10+i]+tbl[40+j]
__global__ void table_kernel(const u32* __restrict__ mask0,
                             const void* wc, const void* bc, const void* wx, const void* bx,
                             const void* wy, const void* by, const void* wcb, const void* bcb,
                             int* __restrict__ flag, float* __restrict__ tbl){
  int bf = (mask0[0] == 0x3F803F80u) ? 1 : 0;
  int e = threadIdx.x;
  if (e == 0) flag[0] = bf;
  if (e < 10)      tbl[e] = ldw(wcb,0,bf)*(ldw(wc,e,bf)+ldw(bc,0,bf)) + ldw(bcb,0,bf);
  else if (e < 40) tbl[e] = ldw(wcb,1,bf)*(ldw(wx,e-10,bf)+ldw(bx,0,bf));
  else if (e < 70) tbl[e] = ldw(wcb,2,bf)*(ldw(wy,e-40,bf)+ldw(by,0,bf));
}

// ---------------- 32x32-tile GEMM, fp32 accum, split-K via gridDim.z, B part-sum folded
// A: [M][K]; AW => weight dtype per flag, else fp32 ws. B: [K][N] likewise (BW),
// nB fp32 parts of stride bStride when BW==0. C: fp32 parts [z][M][N].
template<int AW, int BW>
__launch_bounds__(256)
__global__ void gemm32(const void* __restrict__ A, const void* __restrict__ Bv,
                       float* __restrict__ Cp, int M, int N, int K, int nB, int bStride,
                       const int* __restrict__ flag){
  __shared__ float As[16][33];
  __shared__ float Bs[16][33];
  int bf = flag[0];
  const float* Af = (const float*)A;
  const float* Bf = (const float*)Bv;
  int tid = threadIdx.x;
  int m0 = blockIdx.x*32, n0 = blockIdx.y*32;
  int Z = gridDim.z;
  int kc = (K + Z - 1)/Z;
  int k0 = blockIdx.z*kc, k1 = min(K, k0 + kc);
  float acc[2][2] = {};
  int tm = tid & 15, tn = tid >> 4;
  for (int kb = k0; kb < k1; kb += 16) {
    #pragma unroll
    for (int it = 0; it < 2; it++) {
      int idx = tid + it*256;
      { int kk = idx & 15, m = idx >> 4;         // A: 32 m x 16 k
        float v = 0.f; int gm = m0+m, gk = kb+kk;
        if (gm < M && gk < k1)
          v = AW ? ldw(A, (size_t)gm*K + gk, bf) : Af[(size_t)gm*K + gk];
        As[kk][m] = v; }
      { int n = idx & 31, kk = idx >> 5;         // B: 16 k x 32 n
        float v = 0.f; int gn = n0+n, gk = kb+kk;
        if (gn < N && gk < k1) {
          size_t off = (size_t)gk*N + gn;
          if (BW) v = ldw(Bv, off, bf);
          else for (int s = 0; s < nB; s++) v += Bf[(size_t)s*bStride + off];
        }
        Bs[kk][n] = v; }
    }
    __syncthreads();
    #pragma unroll
    for (int kk = 0; kk < 16; kk++) {
      float a0 = As[kk][tm*2], a1 = As[kk][tm*2+1];
      float b0 = Bs[kk][tn*2], b1 = Bs[kk][tn*2+1];
      acc[0][0] += a0*b0; acc[0][1] += a0*b1;
      acc[1][0] += a1*b0; acc[1][1] += a1*b1;
    }
    __syncthreads();
  }
  float* C = Cp + (size_t)blockIdx.z*M*N;
  #pragma unroll
  for (int i = 0; i < 2; i++)
    #pragma unroll
    for (int j = 0; j < 2; j++) {
      int gm = m0 + tm*2 + i, gn = n0 + tn*2 + j;
      if (gm < M && gn < N) C[(size_t)gm*N + gn] = acc[i][j];
    }
}

// ---------------- Hresh[j*240 + p*40 + n] = sum_{s<8} Hfp[s][(p*300+j)*40 + n]
__global__ void repack_kernel(const float* __restrict__ Hfp, float* __restrict__ Hresh){
  int oi = blockIdx.x*256 + threadIdx.x;
  if (oi >= 72000) return;
  int j = oi/240, c = oi%240, p = c/40, n = c%40;
  float s = 0.f;
  #pragma unroll
  for (int sp = 0; sp < 8; sp++) s += Hfp[(size_t)sp*72000 + (p*300+j)*40 + n];
  Hresh[oi] = s;
}

// ---------------- Wfull[k*40+n], k = p*1720+g*86+t: sum_d wobj[t,d]*R1[(g*50+d)][p*40+n]
__global__ void wfull_kernel(const float* __restrict__ wobj, const float* __restrict__ R1p,
                             float* __restrict__ Wfull){
  int oi = blockIdx.x*256 + threadIdx.x;
  if (oi >= KTOT*NP) return;
  int k = oi/NP, n = oi%NP;
  int p = k/1720, r = k%1720, g = r/86, t = r%86;
  float s = 0.f;
  #pragma unroll 2
  for (int d = 0; d < 50; d++) {
    size_t off = (size_t)(g*50+d)*240 + p*40 + n;
    float rv = R1p[off] + R1p[240000+off] + R1p[480000+off] + R1p[720000+off];
    s += wobj[t*50 + d] * rv;
  }
  Wfull[oi] = s;
}

// ---------------- r1red[j*40+n] = sum over 480 terms (4 parts x 20 g x 6 p), 8-way reduce
__global__ void r1red_kernel(const float* __restrict__ R1p, float* __restrict__ r1red){
  __shared__ float red[8][33];
  int nt = threadIdx.x & 31, rt = threadIdx.x >> 5;
  int oi = blockIdx.x*32 + nt;
  int j = (oi < 2000) ? oi/40 : 0, n = (oi < 2000) ? oi%40 : 0;
  float s = 0.f;
  if (oi < 2000) {
    #pragma unroll 2
    for (int u = rt; u < 480; u += 8) {
      int sp = u/120, rm = u - sp*120, g = rm/6, p = rm - g*6;
      s += R1p[(size_t)sp*240000 + (g*50+j)*240 + p*40 + n];
    }
  }
  red[rt][nt] = s;
  __syncthreads();
  if (rt < 4) red[rt][nt] += red[rt+4][nt];
  __syncthreads();
  if (rt < 2) red[rt][nt] += red[rt+2][nt];
  __syncthreads();
  if (rt == 0 && oi < 2000) r1red[oi] = red[0][nt] + red[1][nt];
}

// ---------------- merged 3-job GEMV: out[n] = b2[n] + sum_k x[k]*W[k*N+n]
__global__ void gemv3_kernel(
    const void* x0, const void* W0, const void* b0, float* o0, int N0, int K0, int xw0,
    const void* x1, const void* W1, const void* b1, float* o1, int N1, int K1, int xw1,
    const void* x2, const void* W2, const void* b2, float* o2, int N2, int K2, int xw2,
    int s1, int s2, const int* __restrict__ flag){
  __shared__ float red[16][17];
  int bf = flag[0];
  int b = blockIdx.x;
  const void *x, *W, *bb; float* o; int N, K, xw, lb;
  if (b < s1)      { x=x0; W=W0; bb=b0; o=o0; N=N0; K=K0; xw=xw0; lb=b; }
  else if (b < s2) { x=x1; W=W1; bb=b1; o=o1; N=N1; K=K1; xw=xw1; lb=b-s1; }
  else             { x=x2; W=W2; bb=b2; o=o2; N=N2; K=K2; xw=xw2; lb=b-s2; }
  int nt = threadIdx.x & 15, kt = threadIdx.x >> 4;
  int n = lb*16 + nt;
  float s = 0.f;
  if (n < N) {
    #pragma unroll 4
    for (int k = kt; k < K; k += 16) {
      float xv = xw ? ldw(x,k,bf) : ((const float*)x)[k];
      s += xv * ldw(W,(size_t)k*N+n,bf);
    }
  }
  red[kt][nt] = s;
  __syncthreads();
  for (int st = 8; st > 0; st >>= 1) {
    if (kt < st) red[kt][nt] += red[kt+st][nt];
    __syncthreads();
  }
  if (kt == 0 && n < N) o[n] = red[0][nt] + ldw(bb,n,bf);
}

// ---------------- final bias combine
__global__ void biasfin_kernel(const float* __restrict__ bch,
                               const float* __restrict__ Hresh,
                               const float* __restrict__ r1red,
                               float* __restrict__ biasf){
  __shared__ float red[4][64];
  int nt = threadIdx.x & 63;
  int kt = threadIdx.x >> 6;
  int n = nt;
  float s = 0.f;
  if (n < NP) {
    for (int j = kt; j < 300; j += 4) {
      float h = 0.f;
      #pragma unroll
      for (int p = 0; p < 6; p++) h += Hresh[j*240 + p*40 + n];
      s += bch[B_BIO + j] * h;
    }
    for (int j = kt; j < 50; j += 4)
      s += bch[B_BOBJ + j] * r1red[j*40 + n];
  }
  red[kt][nt] = s;
  __syncthreads();
  if (kt == 0 && n < NP)
    biasf[n] = red[0][nt]+red[1][nt]+red[2][nt]+red[3][nt] + bch[B_BH + n];
}

// ---------------- gather one int4-quad into vbuf
__device__ __forceinline__ void gquad(int t, int q, int kc0, int task0,
    const int* __restrict__ c_idx, const int* __restrict__ i_idx,
    const int* __restrict__ j_idx, const void* __restrict__ maskv, int bf,
    const float* __restrict__ tbl, float* __restrict__ vbuf){
  int gk = kc0 + (q << 2);
  size_t gb = (size_t)(task0 + t)*KTOT + gk;
  int4 c4 = *(const int4*)(c_idx + gb);
  int4 i4 = *(const int4*)(i_idx + gb);
  int4 j4 = *(const int4*)(j_idx + gb);
  float mv[4];
  if (bf) {
    ushort4 m4 = *(const ushort4*)((const u16*)maskv + gb);
    mv[0]=bf2f(m4.x); mv[1]=bf2f(m4.y); mv[2]=bf2f(m4.z); mv[3]=bf2f(m4.w);
  } else {
    float4 m4 = *(const float4*)((const float*)maskv + gb);
    mv[0]=m4.x; mv[1]=m4.y; mv[2]=m4.z; mv[3]=m4.w;
  }
  int cc[4]={c4.x,c4.y,c4.z,c4.w}, ii[4]={i4.x,i4.y,i4.z,i4.w}, jj[4]={j4.x,j4.y,j4.z,j4.w};
  int kk = q << 2;
  #pragma unroll
  for (int x = 0; x < 4; x++)
    vbuf[(kk+x)*65 + t] = (tbl[cc[x]] + tbl[10+ii[x]] + tbl[40+jj[x]]) * mv[x];
}

// ---------------- main: 512 thr = 8 waves x (64 tasks, 5 cols); partials [seg][col][task]
__launch_bounds__(512, 8)
__global__ void main_gather(const int* __restrict__ c_idx, const int* __restrict__ i_idx,
                            const int* __restrict__ j_idx, const void* __restrict__ maskv,
                            const float* __restrict__ tblg, const float* __restrict__ Wfull,
                            const int* __restrict__ flag, float* __restrict__ part){
  __shared__ float tbl[72];
  __shared__ float vbuf[64*65];
  int bf = flag[0];
  int tid = threadIdx.x;
  if (tid < 70) tbl[tid] = tblg[tid];
  int task0 = blockIdx.x << 6;            // 32 blocks x 64 tasks
  int kseg0 = blockIdx.y * SEGLEN;        // 30 segments x 344
  int lane = tid & 63;                    // task within block
  int ngbase = __builtin_amdgcn_readfirstlane(tid >> 6) * 5;  // wave -> 5 cols
  float acc[5] = {};
  __syncthreads();
  for (int cb = 0; cb < 6; cb++) {
    int kc0 = kseg0 + cb*64;
    int kc = (cb == 5) ? 24 : 64;
    if (kc == 64) {
      #pragma unroll
      for (int it = 0; it < 2; it++) {
        int e4 = tid + it*512;
        gquad(e4 >> 4, e4 & 15, kc0, task0, c_idx, i_idx, j_idx, maskv, bf, tbl, vbuf);
      }
    } else {
      if (tid < 384) {                    // 64 tasks x 6 quads
        int t = (int)((u32)tid / 6u);
        gquad(t, tid - t*6, kc0, task0, c_idx, i_idx, j_idx, maskv, bf, tbl, vbuf);
      }
    }
    __syncthreads();
    const float* Wk = Wfull + (size_t)kc0*NP + ngbase;
    for (int k = 0; k < kc; k++) {
      float v = vbuf[k*65 + lane];
      const float* wr = Wk + k*NP;
      #pragma unroll
      for (int n = 0; n < 5; n++) acc[n] += v * wr[n];
    }
    __syncthreads();
  }
  size_t base = ((size_t)blockIdx.y*NP + ngbase)*BTASK + task0 + lane;
  #pragma unroll
  for (int n = 0; n < 5; n++) part[base + (size_t)n*BTASK] = acc[n];
}

// ---------------- reduce partials + bias, emit FP32; coalesced part reads
__global__ void main_reduce(const float* __restrict__ part, const float* __restrict__ biasf,
                            float* __restrict__ out){
  int id = blockIdx.x*256 + threadIdx.x;      // id = col*2048 + task
  if (id >= BTASK*NP) return;
  int col = id >> 11, t = id & 2047;
  float s = biasf[col];
  #pragma unroll
  for (int z = 0; z < KS; z++) s += part[((size_t)z*NP + col)*BTASK + t];
  out[t*NP + col] = s;
}

extern "C" void kernel_launch(void* const* d_in, const int* in_sizes, int n_in,
                              void* d_out, int out_size, void* d_ws, size_t ws_size,
                              hipStream_t stream){
  const int* c_idx = (const int*)d_in[0];
  const int* i_idx = (const int*)d_in[1];
  const int* j_idx = (const int*)d_in[2];
  const void* mask = d_in[3];
  const void *w_color=d_in[4], *b_color=d_in[5], *w_x=d_in[6], *b_x=d_in[7];
  const void *w_y=d_in[8], *b_y=d_in[9], *w_comb=d_in[10], *b_comb=d_in[11];
  const void *oW1=d_in[12], *ob1=d_in[13], *oW2=d_in[14], *ob2=d_in[15];
  const void *oW3=d_in[16], *ob3=d_in[17];
  const void *ioW1=d_in[18], *iob1=d_in[19], *ioW2=d_in[20], *iob2=d_in[21];
  const void *ioW3=d_in[22], *iob3=d_in[23];
  const void *nW1=d_in[24], *nb1=d_in[25], *nW2=d_in[26], *nb2=d_in[27];
  const void *nW3=d_in[28], *nb3=d_in[29], *nW4=d_in[30], *nb4=d_in[31];

  char* ws = (char*)d_ws;
  float* tblw  = (float*)(ws + OFF_TBL);
  float* Wfull = (float*)(ws + OFF_WF);
  float* Hresh = (float*)(ws + OFF_HR);
  float* wobj  = (float*)(ws + OFF_WO);
  float* r1red = (float*)(ws + OFF_RR);
  float* biasf = (float*)(ws + OFF_BF);
  int*   flag  = (int*)  (ws + OFF_FLG);
  float* o12   = (float*)(ws + OFF_O12);
  float* bch   = (float*)(ws + OFF_BCH);
  float* P     = (float*)(ws + OFF_P);
  float* Q     = (float*)(ws + OFF_Q);
  float* part  = (float*)(ws + OFF_PART);

  table_kernel<<<1, 128, 0, stream>>>((const u32*)mask, w_color, b_color, w_x, b_x,
                                      w_y, b_y, w_comb, b_comb, flag, tblw);
  // obj chain: o12 = oW1@oW2, Wobj = o12@oW3
  gemm32<1,1><<<dim3(3,2,1),  256, 0, stream>>>(oW1, oW2, o12, 86, 50, 86, 1, 0, flag);
  gemm32<0,1><<<dim3(3,2,1),  256, 0, stream>>>(o12, oW3, wobj, 86, 50, 50, 1, 0, flag);
  // head chain (right-assoc, split-K parts): S3 -> P, S2 -> Q, Hfp -> P
  gemm32<1,1><<<dim3(16,2,8), 256, 0, stream>>>(nW3, nW4, P, 512, 40, 256, 1, 0, flag);
  gemm32<1,0><<<dim3(32,2,8), 256, 0, stream>>>(nW2, P, Q, 1024, 40, 512, 8, 512*40, flag);
  gemm32<1,0><<<dim3(57,2,8), 256, 0, stream>>>(nW1, Q, P, 1800, 40, 1024, 8, 1024*40, flag);
  repack_kernel<<<282, 256, 0, stream>>>(P, Hresh);
  // io chain: R3 -> Q, R2 -> P, R1 -> Q
  gemm32<1,0><<<dim3(10,8,8), 256, 0, stream>>>(ioW3, Hresh, Q, 300, 240, 300, 1, 0, flag);
  gemm32<1,0><<<dim3(32,8,4), 256, 0, stream>>>(ioW2, Q, P, 1000, 240, 300, 8, 72000, flag);
  gemm32<1,0><<<dim3(32,8,4), 256, 0, stream>>>(ioW1, P, Q, 1000, 240, 1000, 4, 240000, flag);
  // composed weight (folds R1 parts in Q)
  wfull_kernel<<<1613, 256, 0, stream>>>(wobj, Q, Wfull);
  r1red_kernel<<<63, 256, 0, stream>>>(Q, r1red);
  // bias chain: 3 merged levels
  gemv3_kernel<<<55, 256, 0, stream>>>(
      ob1,  oW2,  ob2,  bch+B_BO1,  50,   86, 1,
      iob1, ioW2, iob2, bch+B_BI1, 300, 1000, 1,
      nb1,  nW2,  nb2,  bch+B_BN1, 512, 1024, 1,
      4, 23, flag);
  gemv3_kernel<<<39, 256, 0, stream>>>(
      bch+B_BO1, oW3,  ob3,  bch+B_BOBJ,  50,  50, 0,
      bch+B_BI1, ioW3, iob3, bch+B_BIO,  300, 300, 0,
      bch+B_BN1, nW3,  nb3,  bch+B_BN2,  256, 512, 0,
      4, 23, flag);
  gemv3_kernel<<<3, 256, 0, stream>>>(
      bch+B_BN2, nW4, nb4, bch+B_BH, 40, 256, 0,
      bch+B_BN2, nW4, nb4, bch+B_BH, 40, 256, 0,
      bch+B_BN2, nW4, nb4, bch+B_BH, 40, 256, 0,
      3, 3, flag);
  biasfin_kernel<<<1, 256, 0, stream>>>(bch, Hresh, r1red, biasf);
  // main pass
  main_gather<<<dim3(32, KS), 512, 0, stream>>>(c_idx, i_idx, j_idx, mask, tblw, Wfull,
                                                flag, part);
  main_reduce<<<320, 256, 0, stream>>>(part, biasf, (float*)d_out);
}